// Round 7
// baseline (2003.312 us; speedup 1.0000x reference)
//
#include <hip/hip_runtime.h>
#include <cstddef>

#define BB 8
#define NN 1024
#define CIN 40
#define CH 64
#define CC 128
#define COUT 9
#define KS 9
#define NL 10
#define HSTEP 0.1f
#define SK 4   // split-K factor for matL

typedef __attribute__((ext_vector_type(8))) short bf16x8;
typedef __attribute__((ext_vector_type(4))) float f32x4;

__device__ __forceinline__ unsigned short f2bf(float f) {
    union { float f; unsigned u; } v;
    v.f = f;
    unsigned u = v.u;
    u += 0x7FFFu + ((u >> 16) & 1u);
    return (unsigned short)(u >> 16);
}
__device__ __forceinline__ float bf2f(unsigned short h) {
    union { unsigned u; float f; } v;
    v.u = ((unsigned)h) << 16;
    return v.f;
}

// ---------------- helpers ----------------
__device__ __forceinline__ float blockSum(float v, float* red) {
    int tid = threadIdx.x;
    red[tid] = v;
    __syncthreads();
    for (int s = 128; s > 0; s >>= 1) {
        if (tid < s) red[tid] += red[tid + s];
        __syncthreads();
    }
    float r = red[0];
    __syncthreads();
    return r;
}

// ---------------- packed bf16 conv weights, hi/lo split ----------------
// Wpc*[lb][o][i*16+kk] = Win[lb][o][i][kk] (kk<9 else 0)          (conv1,  KD=1024)
// Wpt*[lb][i][o*16+kk] = Win[lb][o][i][8-kk] (kk<9 else 0)        (conv1T, KD=2048)
__global__ __launch_bounds__(256) void k_prep_wbf(const float* __restrict__ Win,
                                                  unsigned short* __restrict__ Wpch,
                                                  unsigned short* __restrict__ Wpcl,
                                                  unsigned short* __restrict__ Wpth,
                                                  unsigned short* __restrict__ Wptl) {
    int idx = blockIdx.x * 256 + threadIdx.x;
    const int total = NL * 2 * CC * CH * 16;
    if (idx >= total) return;
    int kk = idx & 15;
    int t = idx >> 4;
    int i = t % CH;  t /= CH;
    int o = t % CC;  t /= CC;
    int lb = t;
    float vc = (kk < 9) ? Win[(((size_t)lb * CC + o) * CH + i) * KS + kk] : 0.f;
    float vt = (kk < 9) ? Win[(((size_t)lb * CC + o) * CH + i) * KS + (8 - kk)] : 0.f;
    unsigned short ch = f2bf(vc);
    unsigned short th = f2bf(vt);
    size_t ic = ((size_t)lb * CC + o) * 1024 + i * 16 + kk;
    size_t it = ((size_t)lb * CH + i) * 2048 + o * 16 + kk;
    Wpch[ic] = ch;
    Wpcl[ic] = f2bf(vc - bf2f(ch));
    Wpth[it] = th;
    Wptl[it] = f2bf(vt - bf2f(th));
}

// bks[lb][o][k] = sum_i Win[lb][o][i][k] * Bias[lb][i]   (exact fp32 bias folding)
__global__ __launch_bounds__(256) void k_prep_bks(const float* __restrict__ Win,
                                                  const float* __restrict__ Bias,
                                                  float* __restrict__ bks) {
    int idx = blockIdx.x * 256 + threadIdx.x;
    const int total = NL * 2 * CC * KS;
    if (idx >= total) return;
    int k = idx % KS;
    int t = idx / KS;
    int o = t % CC;
    int lb = t / CC;
    float s = 0.f;
    for (int i = 0; i < CH; ++i)
        s += Win[(((size_t)lb * CC + o) * CH + i) * KS + k] * Bias[lb * CH + i];
    bks[idx] = s;
}

// ---------------- W fp32 -> bf16 copy ----------------
__global__ __launch_bounds__(256) void k_wtobf(const float* __restrict__ Wg,
                                               unsigned short* __restrict__ Wbf) {
    size_t idx = ((size_t)blockIdx.x * 256 + threadIdx.x) * 4;
    float4 v = *reinterpret_cast<const float4*>(&Wg[idx]);
    ushort4 o;
    o.x = f2bf(v.x); o.y = f2bf(v.y); o.z = f2bf(v.z); o.w = f2bf(v.w);
    *reinterpret_cast<ushort4*>(&Wbf[idx]) = o;
}

// ---------------- open: Z = Kopen @ Zin * mask ----------------
__global__ __launch_bounds__(256) void k_open(const float* __restrict__ Zin,
                                              const float* __restrict__ mask,
                                              const float* __restrict__ Kop,
                                              float* __restrict__ Zcur) {
    int n = blockIdx.x * 256 + threadIdx.x;
    int c = blockIdx.y, b = blockIdx.z;
    float acc = 0.f;
    for (int i = 0; i < CIN; ++i)
        acc += Kop[c * CIN + i] * Zin[((size_t)b * CIN + i) * NN + n];
    Zcur[((size_t)b * CH + c) * NN + n] = acc * mask[b * NN + n];
}

// ---------------- Za ----------------
__global__ __launch_bounds__(256) void k_za(const float* __restrict__ Zcur,
                                            const float* __restrict__ mask,
                                            float* __restrict__ Za) {
    __shared__ float red[256];
    int c = blockIdx.x;  // 0..64
    int b = blockIdx.y;
    int tid = threadIdx.x;
    const float* m = mask + b * NN;
    float x[4], mv[4];
    if (c < CH) {
        const float* src = Zcur + ((size_t)b * CH + c) * NN;
#pragma unroll
        for (int j = 0; j < 4; ++j) { int n = tid * 4 + j; x[j] = src[n]; mv[j] = m[n]; }
    } else {
#pragma unroll
        for (int j = 0; j < 4; ++j) { int n = tid * 4 + j; mv[j] = m[n]; x[j] = 0.5f * ((float)n / 1023.f) * mv[j]; }
    }
    float sm = 0.f, sxm = 0.f;
#pragma unroll
    for (int j = 0; j < 4; ++j) { sm += mv[j]; sxm += x[j] * mv[j]; }
    float msum = blockSum(sm, red);
    float xm = blockSum(sxm, red);
    if (c < CH) {
        float mean = xm / msum;
        float ss = 0.f;
#pragma unroll
        for (int j = 0; j < 4; ++j) { x[j] -= mean * mv[j]; ss += x[j] * x[j]; }
        ss = blockSum(ss, red);
        float sc = rsqrtf(ss / msum + 1e-4f);
#pragma unroll
        for (int j = 0; j < 4; ++j) x[j] *= sc;
    }
    float ps = 0.f;
#pragma unroll
    for (int j = 0; j < 4; ++j) ps += x[j];
    float pm = blockSum(ps, red) / (float)NN;
    float* dst = Za + ((size_t)b * 65 + c) * NN;
#pragma unroll
    for (int j = 0; j < 4; ++j) dst[tid * 4 + j] = x[j] - pm;
}

// ---------------- n2 ----------------
__global__ __launch_bounds__(256) void k_n2g(const float* __restrict__ Za, float* __restrict__ n2g) {
    int n = blockIdx.x * 256 + threadIdx.x;
    int b = blockIdx.y;
    float s = 0.f;
    for (int c = 0; c < 65; ++c) { float v = Za[((size_t)b * 65 + c) * NN + n]; s += v * v; }
    n2g[b * NN + n] = s;
}

// ---------------- Gram + W ----------------
__global__ __launch_bounds__(256) void k_gramW(const float* __restrict__ Za,
                                               const float* __restrict__ n2g,
                                               const float* __restrict__ mask,
                                               float* __restrict__ Wg) {
    __shared__ float As[65][64];
    __shared__ float Bs2[65][64];
    int i0 = blockIdx.x * 64, j0 = blockIdx.y * 64, b = blockIdx.z;
    int tid = threadIdx.x;
    for (int e = tid; e < 65 * 64; e += 256) {
        int c = e >> 6, t = e & 63;
        const float* src = Za + ((size_t)b * 65 + c) * NN;
        As[c][t] = src[i0 + t];
        Bs2[c][t] = src[j0 + t];
    }
    __syncthreads();
    int tx = tid & 15, ty = tid >> 4;
    float acc[4][4] = {};
    for (int c = 0; c < 65; ++c) {
        float a[4];
#pragma unroll
        for (int q = 0; q < 4; ++q) a[q] = As[c][ty * 4 + q];
        float bv[4];
        *reinterpret_cast<float4*>(bv) = *reinterpret_cast<const float4*>(&Bs2[c][tx * 4]);
#pragma unroll
        for (int q = 0; q < 4; ++q)
#pragma unroll
            for (int r = 0; r < 4; ++r) acc[q][r] += a[q] * bv[r];
    }
    const float* m = mask + b * NN;
    for (int q = 0; q < 4; ++q) {
        int i = i0 + ty * 4 + q;
        float n2i = n2g[b * NN + i], mi = m[i];
        float res[4];
#pragma unroll
        for (int r = 0; r < 4; ++r) {
            int j = j0 + tx * 4 + r;
            float D = n2i + n2g[b * NN + j] - 2.f * acc[q][r];
            D *= (3.f / 65.f);
            D = fmaxf(D, 0.f);
            float dist = (D > 0.f) ? sqrtf(D) : 0.f;
            float mmv = mi * m[j];
            res[r] = expf(-dist * mmv) * mmv;
        }
        *reinterpret_cast<float4*>(&Wg[((size_t)b * NN + i) * NN + j0 + tx * 4]) =
            *reinterpret_cast<float4*>(res);
    }
}

// ---------------- Wsum: two-phase column sums ----------------
__global__ __launch_bounds__(256) void k_wsum_part(const float* __restrict__ Wg,
                                                   float* __restrict__ Wsp) {
    int j = blockIdx.x * 256 + threadIdx.x;
    int ch = blockIdx.y;   // 16 chunks of 64 rows
    int b = blockIdx.z;
    float s = 0.f;
    int i0 = ch * 64;
#pragma unroll 8
    for (int i = 0; i < 64; ++i) s += Wg[((size_t)b * NN + i0 + i) * NN + j];
    Wsp[((size_t)b * 16 + ch) * NN + j] = s;
}
__global__ __launch_bounds__(256) void k_wsum_fin(const float* __restrict__ Wsp,
                                                  float* __restrict__ Wsum) {
    int j = blockIdx.x * 256 + threadIdx.x;
    int b = blockIdx.y;
    float s = 0.f;
#pragma unroll
    for (int ch = 0; ch < 16; ++ch) s += Wsp[((size_t)b * 16 + ch) * NN + j];
    Wsum[b * NN + j] = s;
}

// ---------------- MFMA implicit-GEMM conv, hi/lo-compensated bf16 ----------------
// GEMM kdim = chan*16 + kk (kk>=9 zero-padded). 64-row x 32-n block, 4 waves.
// X staged in LDS as uint = (lo16<<16)|hi16; W pre-split hi/lo.
// Whi*Xhi + Wlo*Xhi + Whi*Xlo (3 MFMAs) -> ~fp32 accuracy.
// MODE 0 (conv1, KD=1024): y = (br<<1)|o_half; in InA(64ch); bias; mask if br==0.
// MODE 1 (conv1T, KD=2048): y = (br<<1)|kh; in (br?InB:InA)+kh*64 rows; out partial [kh].
template <int KD, int MODE>
__global__ __launch_bounds__(256) void k_conv_mfma(const float* __restrict__ InA,
                                                   const float* __restrict__ InB,
                                                   const unsigned short* __restrict__ Wh,
                                                   const unsigned short* __restrict__ Wlo,
                                                   const float* __restrict__ bksl,
                                                   const float* __restrict__ mask,
                                                   float* __restrict__ OutA0,
                                                   float* __restrict__ OutA1,
                                                   float* __restrict__ OutB0,
                                                   float* __restrict__ OutB1) {
    constexpr int XW = 48;
    __shared__ __align__(16) unsigned int xs[64][XW];  // (lo<<16)|hi
    int n0 = blockIdx.x * 32;
    int y = blockIdx.y;
    int b = blockIdx.z;
    int tid = threadIdx.x;

    const float* Xb;
    size_t wbase;
    int kbase;
    float* Outp;
    const float* bo_base = nullptr;
    int domask = 0;
    if (MODE == 0) {
        int br = y >> 1, ol = (y & 1) * 64;
        Xb = InA + (size_t)b * CH * NN;
        wbase = ((size_t)br * CC + ol) * KD;
        kbase = 0;
        Outp = (br ? OutB0 : OutA0) + ((size_t)b * CC + ol) * NN;
        bo_base = bksl + (br * CC + ol) * KS;
        domask = (br == 0);
    } else {
        int br = y >> 1, kh = y & 1;
        Xb = (br ? InB : InA) + (size_t)b * CC * NN + (size_t)kh * 64 * NN;
        wbase = (size_t)br * CH * KD;
        kbase = kh * 1024;
        float* o0 = br ? OutB0 : OutA0;
        float* o1 = br ? OutB1 : OutA1;
        Outp = (kh ? o1 : o0) + (size_t)b * CH * NN;
    }

    // stage 64 input rows (4-halo each side; zero out-of-range), hi/lo packed per uint
    for (int e = tid * 4; e < 64 * XW; e += 1024) {
        int i = e / XW, t = e - i * XW;
        int gn = n0 + t - 4;
        float4 v = make_float4(0.f, 0.f, 0.f, 0.f);
        if (gn >= 0 && gn + 3 < NN) v = *reinterpret_cast<const float4*>(&Xb[(size_t)i * NN + gn]);
        uint4 u;
        unsigned short h;
        h = f2bf(v.x); u.x = (unsigned)h | ((unsigned)f2bf(v.x - bf2f(h)) << 16);
        h = f2bf(v.y); u.y = (unsigned)h | ((unsigned)f2bf(v.y - bf2f(h)) << 16);
        h = f2bf(v.z); u.z = (unsigned)h | ((unsigned)f2bf(v.z - bf2f(h)) << 16);
        h = f2bf(v.w); u.w = (unsigned)h | ((unsigned)f2bf(v.w - bf2f(h)) << 16);
        *reinterpret_cast<uint4*>(&xs[i][t]) = u;
    }
    __syncthreads();

    int wid = tid >> 6, lane = tid & 63;
    int wo = (wid >> 1) * 32, wn = (wid & 1) * 16;
    int r = lane & 15, g = lane >> 4;
    f32x4 acc[2] = {};
#pragma unroll 2
    for (int s = 0; s < 32; ++s) {
        bf16x8 ah[2], al[2];
        const unsigned short* w0 = Wh + wbase + (size_t)(wo + r) * KD + kbase + s * 32 + g * 8;
        const unsigned short* w1 = Wh + wbase + (size_t)(wo + 16 + r) * KD + kbase + s * 32 + g * 8;
        const unsigned short* l0 = Wlo + wbase + (size_t)(wo + r) * KD + kbase + s * 32 + g * 8;
        const unsigned short* l1 = Wlo + wbase + (size_t)(wo + 16 + r) * KD + kbase + s * 32 + g * 8;
        ah[0] = *reinterpret_cast<const bf16x8*>(w0);
        ah[1] = *reinterpret_cast<const bf16x8*>(w1);
        al[0] = *reinterpret_cast<const bf16x8*>(l0);
        al[1] = *reinterpret_cast<const bf16x8*>(l1);
        const unsigned int* xrow = xs[2 * s + (g >> 1)];
        int off = wn + r + ((g & 1) << 3);
        bf16x8 bh, bl;
#pragma unroll
        for (int j = 0; j < 8; ++j) {
            unsigned u = xrow[off + j];
            bh[j] = (short)(u & 0xFFFFu);
            bl[j] = (short)(u >> 16);
        }
#pragma unroll
        for (int fc = 0; fc < 2; ++fc) {
            acc[fc] = __builtin_amdgcn_mfma_f32_16x16x32_bf16(ah[fc], bh, acc[fc], 0, 0, 0);
            acc[fc] = __builtin_amdgcn_mfma_f32_16x16x32_bf16(al[fc], bh, acc[fc], 0, 0, 0);
            acc[fc] = __builtin_amdgcn_mfma_f32_16x16x32_bf16(ah[fc], bl, acc[fc], 0, 0, 0);
        }
    }

    const float* mrow = mask + b * NN;
    int n = n0 + wn + r;
#pragma unroll
    for (int fc = 0; fc < 2; ++fc) {
#pragma unroll
        for (int rr = 0; rr < 4; ++rr) {
            int oo = wo + fc * 16 + 4 * g + rr;
            float v = acc[fc][rr];
            if (MODE == 0) {
                const float* bo = bo_base + oo * KS;
                float bias = 0.f;
#pragma unroll
                for (int k = 0; k < KS; ++k) {
                    int nn2 = n + k - 4;
                    if (nn2 >= 0 && nn2 < NN) bias += bo[k];
                }
                v += bias;
                if (domask) v *= mrow[n];
            }
            Outp[(size_t)oo * NN + n] = v;
        }
    }
}

// ---------------- MFMA split-K X@W partials (X optionally = XA+XB) ----------------
__global__ __launch_bounds__(256) void k_matL_mfma(const float* __restrict__ X,
                                                   const float* __restrict__ XB,
                                                   const unsigned short* __restrict__ Wbf,
                                                   float* __restrict__ Part, int rows) {
    __shared__ __align__(16) float Xs[64][36];
    int cb = rows >> 6;
    int n0 = blockIdx.x * 64;
    int sk = blockIdx.y;
    int b = blockIdx.z / cb;
    int c0 = (blockIdx.z % cb) * 64;
    int tid = threadIdx.x;
    int wid = tid >> 6, lane = tid & 63;
    int wc = (wid >> 1) * 32, wn = (wid & 1) * 32;
    int r = lane & 15, g = lane >> 4;
    const float* Xb = X + (size_t)b * rows * NN;
    const float* Xb2 = XB ? XB + (size_t)b * rows * NN : nullptr;
    const unsigned short* Wb = Wbf + (size_t)b * NN * NN;

    f32x4 acc[2][2] = {};
    int m_beg = sk * (NN / SK);
    for (int m0 = m_beg; m0 < m_beg + NN / SK; m0 += 32) {
        if (Xb2) {
            for (int e = tid; e < 2048; e += 256) {
                int cc = e >> 5, mm = e & 31;
                Xs[cc][mm] = Xb[(size_t)(c0 + cc) * NN + m0 + mm] + Xb2[(size_t)(c0 + cc) * NN + m0 + mm];
            }
        } else {
            for (int e = tid; e < 2048; e += 256) {
                int cc = e >> 5, mm = e & 31;
                Xs[cc][mm] = Xb[(size_t)(c0 + cc) * NN + m0 + mm];
            }
        }
        __syncthreads();
        bf16x8 afr[2];
#pragma unroll
        for (int fc = 0; fc < 2; ++fc) {
            const float4* p = reinterpret_cast<const float4*>(&Xs[wc + fc * 16 + r][8 * g]);
            float4 v0 = p[0], v1 = p[1];
            bf16x8 a;
            a[0] = (short)f2bf(v0.x); a[1] = (short)f2bf(v0.y);
            a[2] = (short)f2bf(v0.z); a[3] = (short)f2bf(v0.w);
            a[4] = (short)f2bf(v1.x); a[5] = (short)f2bf(v1.y);
            a[6] = (short)f2bf(v1.z); a[7] = (short)f2bf(v1.w);
            afr[fc] = a;
        }
        bf16x8 bfr[2];
#pragma unroll
        for (int fn = 0; fn < 2; ++fn) {
            int ncol = n0 + wn + fn * 16 + r;
            bfr[fn] = *reinterpret_cast<const bf16x8*>(&Wb[(size_t)ncol * NN + m0 + 8 * g]);
        }
#pragma unroll
        for (int fc = 0; fc < 2; ++fc)
#pragma unroll
            for (int fn = 0; fn < 2; ++fn)
                acc[fc][fn] = __builtin_amdgcn_mfma_f32_16x16x32_bf16(afr[fc], bfr[fn], acc[fc][fn], 0, 0, 0);
        __syncthreads();
    }
#pragma unroll
    for (int fc = 0; fc < 2; ++fc)
#pragma unroll
        for (int fn = 0; fn < 2; ++fn) {
            int ncol = n0 + wn + fn * 16 + r;
#pragma unroll
            for (int rr = 0; rr < 4; ++rr) {
                int crow = c0 + wc + fc * 16 + 4 * g + rr;
                Part[(((size_t)b * SK + sk) * rows + crow) * NN + ncol] = acc[fc][fn][rr];
            }
        }
}

// ---------------- reduce partials + epilogue ----------------
__global__ __launch_bounds__(256) void k_matL_fin(const float* __restrict__ X,
                                                  const float* __restrict__ XB,
                                                  const float* __restrict__ Part,
                                                  const float* __restrict__ Wsum,
                                                  const float* __restrict__ mask,
                                                  const float* __restrict__ T0A,
                                                  const float* __restrict__ T0B,
                                                  float* __restrict__ Out, int rows, int mode) {
    int idx = blockIdx.x * 256 + threadIdx.x;
    int b = blockIdx.y;
    if (idx >= rows * NN / 4) return;
    int c = idx / (NN / 4);
    int n = (idx % (NN / 4)) * 4;
    float4 s = make_float4(0.f, 0.f, 0.f, 0.f);
#pragma unroll
    for (int sk = 0; sk < SK; ++sk) {
        float4 p = *reinterpret_cast<const float4*>(
            &Part[(((size_t)b * SK + sk) * rows + c) * NN + n]);
        s.x += p.x; s.y += p.y; s.z += p.z; s.w += p.w;
    }
    float4 xv = *reinterpret_cast<const float4*>(&X[((size_t)b * rows + c) * NN + n]);
    if (XB) {
        float4 x2 = *reinterpret_cast<const float4*>(&XB[((size_t)b * rows + c) * NN + n]);
        xv.x += x2.x; xv.y += x2.y; xv.z += x2.z; xv.w += x2.w;
    }
    float4 wv = *reinterpret_cast<const float4*>(&Wsum[b * NN + n]);
    float4 mv = *reinterpret_cast<const float4*>(&mask[b * NN + n]);
    float y0 = xv.x * wv.x - s.x, y1 = xv.y * wv.y - s.y;
    float y2 = xv.z * wv.z - s.z, y3 = xv.w * wv.w - s.w;
    float4 res;
    if (mode == 0) {
        res = make_float4(y0 * mv.x, y1 * mv.y, y2 * mv.z, y3 * mv.w);
    } else {
        float4 t0 = *reinterpret_cast<const float4*>(&T0A[((size_t)b * rows + c) * NN + n]);
        float4 t0b = *reinterpret_cast<const float4*>(&T0B[((size_t)b * rows + c) * NN + n]);
        t0.x += t0b.x; t0.y += t0b.y; t0.z += t0b.z; t0.w += t0b.w;
        float4 o = *reinterpret_cast<const float4*>(&Out[((size_t)b * rows + c) * NN + n]);
        res = make_float4(o.x - HSTEP * mv.x * (t0.x + y0),
                          o.y - HSTEP * mv.y * (t0.y + y1),
                          o.z - HSTEP * mv.z * (t0.z + y2),
                          o.w - HSTEP * mv.w * (t0.w + y3));
    }
    *reinterpret_cast<float4*>(&Out[((size_t)b * rows + c) * NN + n]) = res;
}

// ---------------- masked row mean (two tensors fused) ----------------
__global__ __launch_bounds__(256) void k_rowmean2(const float* __restrict__ X0,
                                                  const float* __restrict__ X1,
                                                  const float* __restrict__ mask,
                                                  float* __restrict__ meanA) {
    __shared__ float red[256];
    int c = blockIdx.x, b = blockIdx.y, z = blockIdx.z, tid = threadIdx.x;
    const float* src = (z ? X1 : X0) + ((size_t)b * CC + c) * NN;
    const float* m = mask + b * NN;
    float s = 0.f, sm = 0.f;
    for (int n = tid; n < NN; n += 256) { float mv = m[n]; s += src[n] * mv; sm += mv; }
    float ts = blockSum(s, red);
    float tm = blockSum(sm, red);
    if (tid == 0) meanA[((size_t)z * BB + b) * CC + c] = ts / tm;
}

// ---------------- colnorm (32n x 8 c-groups per block) ----------------
__global__ __launch_bounds__(256) void k_colnorm2(float* __restrict__ X0,
                                                  float* __restrict__ X1,
                                                  const float* __restrict__ mask,
                                                  const float* __restrict__ meanA) {
    __shared__ float red[8][32];
    int tid = threadIdx.x;
    int nl = tid & 31, cg = tid >> 5;
    int n = blockIdx.x * 32 + nl;
    int b = blockIdx.y, z = blockIdx.z;
    float* X = (z ? X1 : X0) + (size_t)b * CC * NN;
    const float* me = meanA + ((size_t)z * BB + b) * CC;
    float mv = mask[b * NN + n];
    float ss = 0.f;
#pragma unroll
    for (int cc = 0; cc < 16; ++cc) {
        int c = cg * 16 + cc;
        float v = (X[(size_t)c * NN + n] - me[c]) * mv;
        ss += v * v;
    }
    red[cg][nl] = ss;
    __syncthreads();
    if (cg < 4) red[cg][nl] += red[cg + 4][nl];
    __syncthreads();
    if (cg < 2) red[cg][nl] += red[cg + 2][nl];
    __syncthreads();
    if (cg < 1) red[0][nl] += red[1][nl];
    __syncthreads();
    float inv = rsqrtf(red[0][nl] + 0.001f);
#pragma unroll
    for (int cc = 0; cc < 16; ++cc) {
        int c = cg * 16 + cc;
        float v = (X[(size_t)c * NN + n] - me[c]) * mv;
        X[(size_t)c * NN + n] = fmaxf(v * inv, 0.f);
    }
}

// ---------------- close (64n x 4 c-groups) ----------------
__global__ __launch_bounds__(256) void k_close(const float* __restrict__ Zcur,
                                               const float* __restrict__ Kcl,
                                               const float* __restrict__ mask,
                                               float* __restrict__ Zout) {
    __shared__ float red[4][64][COUT];
    int tid = threadIdx.x;
    int nl = tid & 63, cg = tid >> 6;
    int n = blockIdx.x * 64 + nl;
    int b = blockIdx.y;
    float acc[COUT] = {};
#pragma unroll
    for (int cc = 0; cc < 16; ++cc) {
        int c = cg * 16 + cc;
        float zv = Zcur[((size_t)b * CH + c) * NN + n];
#pragma unroll
        for (int o = 0; o < COUT; ++o) acc[o] += Kcl[o * CH + c] * zv;
    }
#pragma unroll
    for (int o = 0; o < COUT; ++o) red[cg][nl][o] = acc[o];
    __syncthreads();
    if (cg == 0) {
        float mv = mask[b * NN + n];
#pragma unroll
        for (int o = 0; o < COUT; ++o) {
            float s = red[0][nl][o] + red[1][nl][o] + red[2][nl][o] + red[3][nl][o];
            Zout[((size_t)b * COUT + o) * NN + n] = s * mv;
        }
    }
}

// ---------------- center3 ----------------
__global__ __launch_bounds__(256) void k_center3(const float* __restrict__ Zout, float* __restrict__ Zc3) {
    __shared__ float red[256];
    int c = blockIdx.x, b = blockIdx.y, tid = threadIdx.x;
    const float* src = Zout + ((size_t)b * COUT + c) * NN;
    float s = 0.f;
    for (int n = tid; n < NN; n += 256) s += src[n];
    float mean = blockSum(s, red) / (float)NN;
    float* dst = Zc3 + ((size_t)b * COUT + c) * NN;
    for (int n = tid; n < NN; n += 256) dst[n] = src[n] - mean;
}

__global__ __launch_bounds__(256) void k_n23(const float* __restrict__ Zc3, float* __restrict__ n23) {
    int n = blockIdx.x * 256 + threadIdx.x;
    int g = blockIdx.y, b = blockIdx.z;
    float s = 0.f;
#pragma unroll
    for (int c = 0; c < 3; ++c) { float v = Zc3[((size_t)b * COUT + g * 3 + c) * NN + n]; s += v * v; }
    n23[((size_t)b * 3 + g) * NN + n] = s;
}

// ---------------- final pairwise distances ----------------
__global__ __launch_bounds__(256) void k_dist(const float* __restrict__ Zc3,
                                              const float* __restrict__ n23,
                                              float* __restrict__ dout) {
    __shared__ float Ai[3][64], Aj[3][64], ni[64], nj[64];
    int bg = blockIdx.z;
    int b = bg / 3, g = bg - 3 * b;
    int i0 = blockIdx.x * 64, j0 = blockIdx.y * 64;
    int tid = threadIdx.x;
    if (tid < 64) ni[tid] = n23[((size_t)b * 3 + g) * NN + i0 + tid];
    else if (tid < 128) { int t = tid - 64; nj[t] = n23[((size_t)b * 3 + g) * NN + j0 + t]; }
    for (int e = tid; e < 192; e += 256) {
        int c = e / 64, t = e - c * 64;
        Ai[c][t] = Zc3[((size_t)b * COUT + g * 3 + c) * NN + i0 + t];
    }
    for (int e = tid; e < 192; e += 256) {
        int c = e / 64, t = e - c * 64;
        Aj[c][t] = Zc3[((size_t)b * COUT + g * 3 + c) * NN + j0 + t];
    }
    __syncthreads();
    int tx = tid & 15, ty = tid >> 4;
    for (int q = 0; q < 4; ++q) {
        int i = ty * 4 + q;
        float a0 = Ai[0][i], a1 = Ai[1][i], a2 = Ai[2][i], n2i = ni[i];
        float res[4];
#pragma unroll
        for (int r = 0; r < 4; ++r) {
            int j = tx * 4 + r;
            float D = n2i + nj[j] - 2.f * (a0 * Aj[0][j] + a1 * Aj[1][j] + a2 * Aj[2][j]);
            D = fmaxf(D, 0.f);
            res[r] = (D > 0.f) ? sqrtf(D) : 0.f;
        }
        *reinterpret_cast<float4*>(&dout[(((size_t)b * 3 + g) * NN + i0 + i) * NN + j0 + tx * 4]) =
            *reinterpret_cast<float4*>(res);
    }
}

// ---------------- driver ----------------
extern "C" void kernel_launch(void* const* d_in, const int* in_sizes, int n_in,
                              void* d_out, int out_size, void* d_ws, size_t ws_size,
                              hipStream_t stream) {
    (void)in_sizes; (void)n_in; (void)out_size; (void)ws_size;
    const float* Zin  = (const float*)d_in[0];
    const float* mask = (const float*)d_in[1];
    const float* Kop  = (const float*)d_in[2];
    const float* Kcl  = (const float*)d_in[3];
    const float* Win  = (const float*)d_in[4];
    const float* Bias = (const float*)d_in[5];
    float* out = (float*)d_out;
    float* ws = (float*)d_ws;

    size_t off = 0;
    float* Zcur = ws + off;  off += (size_t)BB * CH * NN;
    float* C0   = ws + off;  off += (size_t)BB * CC * NN;
    float* C1   = ws + off;  off += (size_t)BB * CC * NN;
    float* A1   = ws + off;  off += (size_t)BB * CC * NN;
    float* T0A  = ws + off;  off += (size_t)BB * CH * NN;
    float* T1pA = ws + off;  off += (size_t)BB * CH * NN;
    float* Za   = ws + off;  off += (size_t)BB * 65 * NN;
    float* n2g  = ws + off;  off += (size_t)BB * NN;
    float* Wg   = ws + off;  off += (size_t)BB * NN * NN;
    float* Wsum = ws + off;  off += (size_t)BB * NN;
    float* meanA= ws + off;  off += (size_t)2 * BB * CC;
    float* bks  = ws + off;  off += (size_t)NL * 2 * CC * KS;
    float* Zc3  = ws + off;  off += (size_t)BB * COUT * NN;
    float* n23  = ws + off;  off += (size_t)BB * 3 * NN;
    float* Wsp  = ws + off;  off += (size_t)BB * 16 * NN;

    // Scratch in the (as-yet-unwritten) dists region of d_out (25,165,824 floats):
    // Part  [0 .. 4,194,304)
    // Wbf   [4,194,304 .. 8,388,608)
    // Wpch  [8,388,608 .. 9,699,328)
    // Wpcl  [9,699,328 .. 11,010,048)
    // Wpth  [11,010,048 .. 12,320,768)
    // Wptl  [12,320,768 .. 13,631,488)
    // T0B   [13,631,488 .. 14,155,776)
    // T1pB  [14,155,776 .. 14,680,064)
    float* Part = out;
    unsigned short* Wbf  = (unsigned short*)(out + (size_t)4194304);
    unsigned short* Wpch = (unsigned short*)(out + (size_t)8388608);
    unsigned short* Wpcl = (unsigned short*)(out + (size_t)9699328);
    unsigned short* Wpth = (unsigned short*)(out + (size_t)11010048);
    unsigned short* Wptl = (unsigned short*)(out + (size_t)12320768);
    float* T0B  = out + (size_t)13631488;
    float* T1pB = out + (size_t)14155776;

    k_prep_wbf<<<dim3((NL * 2 * CC * CH * 16 + 255) / 256), 256, 0, stream>>>(Win, Wpch, Wpcl, Wpth, Wptl);
    k_prep_bks<<<dim3((NL * 2 * CC * KS + 255) / 256), 256, 0, stream>>>(Win, Bias, bks);
    k_open<<<dim3(NN / 256, CH, BB), 256, 0, stream>>>(Zin, mask, Kop, Zcur);
    k_za<<<dim3(65, BB), 256, 0, stream>>>(Zcur, mask, Za);
    k_n2g<<<dim3(NN / 256, BB), 256, 0, stream>>>(Za, n2g);
    k_gramW<<<dim3(16, 16, BB), 256, 0, stream>>>(Za, n2g, mask, Wg);
    k_wsum_part<<<dim3(NN / 256, 16, BB), 256, 0, stream>>>(Wg, Wsp);
    k_wsum_fin<<<dim3(NN / 256, BB), 256, 0, stream>>>(Wsp, Wsum);
    k_wtobf<<<dim3((int)((size_t)BB * NN * NN / 4 / 256)), 256, 0, stream>>>(Wg, Wbf);

    for (int l = 0; l < NL; ++l) {
        const unsigned short* Wpch_l = Wpch + (size_t)l * 2 * CC * 1024;
        const unsigned short* Wpcl_l = Wpcl + (size_t)l * 2 * CC * 1024;
        const unsigned short* Wpth_l = Wpth + (size_t)l * 2 * CH * 2048;
        const unsigned short* Wptl_l = Wptl + (size_t)l * 2 * CH * 2048;
        const float* bksl = bks + (size_t)l * 2 * CC * KS;

        k_conv_mfma<1024, 0><<<dim3(NN / 32, 4, BB), 256, 0, stream>>>(
            Zcur, nullptr, Wpch_l, Wpcl_l, bksl, mask, C0, nullptr, C1, nullptr);
        k_matL_mfma<<<dim3(NN / 64, SK, BB * (CC / 64)), 256, 0, stream>>>(C1, nullptr, Wbf, Part, CC);
        k_matL_fin<<<dim3(CC * NN / 4 / 256, BB), 256, 0, stream>>>(
            C1, nullptr, Part, Wsum, mask, nullptr, nullptr, A1, CC, 0);
        k_rowmean2<<<dim3(CC, BB, 2), 256, 0, stream>>>(C0, A1, mask, meanA);
        k_colnorm2<<<dim3(NN / 32, BB, 2), 256, 0, stream>>>(C0, A1, mask, meanA);
        k_conv_mfma<2048, 1><<<dim3(NN / 32, 4, BB), 256, 0, stream>>>(
            C0, A1, Wpth_l, Wptl_l, nullptr, mask, T0A, T0B, T1pA, T1pB);
        k_matL_mfma<<<dim3(NN / 64, SK, BB * (CH / 64)), 256, 0, stream>>>(T1pA, T1pB, Wbf, Part, CH);
        k_matL_fin<<<dim3(CH * NN / 4 / 256, BB), 256, 0, stream>>>(
            T1pA, T1pB, Part, Wsum, mask, T0A, T0B, Zcur, CH, 1);
    }

    float* Zout = out + (size_t)BB * 3 * NN * NN;
    k_close<<<dim3(NN / 64, BB), 256, 0, stream>>>(Zcur, Kcl, mask, Zout);
    k_center3<<<dim3(COUT, BB), 256, 0, stream>>>(Zout, Zc3);
    k_n23<<<dim3(NN / 256, 3, BB), 256, 0, stream>>>(Zc3, n23);
    k_dist<<<dim3(16, 16, 3 * BB), 256, 0, stream>>>(Zc3, n23, out);
}

// Round 8
// 1024.608 us; speedup vs baseline: 1.9552x; 1.9552x over previous
//
#include <hip/hip_runtime.h>
#include <cstddef>

#define BB 8
#define NN 1024
#define CIN 40
#define CH 64
#define CC 128
#define COUT 9
#define KS 9
#define NL 10
#define HSTEP 0.1f
#define SK 4   // split-K factor for matL

typedef __attribute__((ext_vector_type(8))) short bf16x8;
typedef __attribute__((ext_vector_type(4))) float f32x4;

__device__ __forceinline__ unsigned short f2bf(float f) {
    union { float f; unsigned u; } v;
    v.f = f;
    unsigned u = v.u;
    u += 0x7FFFu + ((u >> 16) & 1u);
    return (unsigned short)(u >> 16);
}
__device__ __forceinline__ float bf2f(unsigned short h) {
    union { unsigned u; float f; } v;
    v.u = ((unsigned)h) << 16;
    return v.f;
}

// ---------------- helpers ----------------
__device__ __forceinline__ float blockSum(float v, float* red) {
    int tid = threadIdx.x;
    red[tid] = v;
    __syncthreads();
    for (int s = 128; s > 0; s >>= 1) {
        if (tid < s) red[tid] += red[tid + s];
        __syncthreads();
    }
    float r = red[0];
    __syncthreads();
    return r;
}

// ---------------- packed bf16 conv weights, hi/lo split (row-major stage) ----------------
// Wpc*[lb][o][i*16+kk] = Win[lb][o][i][kk] (kk<9 else 0)          (conv1,  KD=1024)
// Wpt*[lb][i][o*16+kk] = Win[lb][o][i][8-kk] (kk<9 else 0)        (conv1T, KD=2048)
__global__ __launch_bounds__(256) void k_prep_wbf(const float* __restrict__ Win,
                                                  unsigned short* __restrict__ Wpch,
                                                  unsigned short* __restrict__ Wpcl,
                                                  unsigned short* __restrict__ Wpth,
                                                  unsigned short* __restrict__ Wptl) {
    int idx = blockIdx.x * 256 + threadIdx.x;
    const int total = NL * 2 * CC * CH * 16;
    if (idx >= total) return;
    int kk = idx & 15;
    int t = idx >> 4;
    int i = t % CH;  t /= CH;
    int o = t % CC;  t /= CC;
    int lb = t;
    float vc = (kk < 9) ? Win[(((size_t)lb * CC + o) * CH + i) * KS + kk] : 0.f;
    float vt = (kk < 9) ? Win[(((size_t)lb * CC + o) * CH + i) * KS + (8 - kk)] : 0.f;
    unsigned short ch = f2bf(vc);
    unsigned short th = f2bf(vt);
    size_t ic = ((size_t)lb * CC + o) * 1024 + i * 16 + kk;
    size_t it = ((size_t)lb * CH + i) * 2048 + o * 16 + kk;
    Wpch[ic] = ch;
    Wpcl[ic] = f2bf(vc - bf2f(ch));
    Wpth[it] = th;
    Wptl[it] = f2bf(vt - bf2f(th));
}

// ---------------- generic fragment-coalesced re-pack ----------------
// src row-major [LB][R][KDv] bf16 -> dst chunks:
// flat_chunk = (((lb*(R/32)+t32)*(KDv/32)+s)*2+fc)*64 + lane, 8 shorts each
// row = t32*32 + fc*16 + (lane&15), col = s*32 + (lane>>4)*8
__global__ __launch_bounds__(256) void k_packw(const unsigned short* __restrict__ src,
                                               unsigned short* __restrict__ dst,
                                               int R, int KDv, int LB) {
    int idx = blockIdx.x * 256 + threadIdx.x;
    int total = LB * R * KDv / 8;
    if (idx >= total) return;
    int lane = idx & 63;
    int t = idx >> 6;
    int fc = t & 1; t >>= 1;
    int s = t % (KDv / 32); t /= (KDv / 32);
    int t32 = t % (R / 32);
    int lb = t / (R / 32);
    int r = lane & 15, g = lane >> 4;
    int row = t32 * 32 + fc * 16 + r;
    int col = s * 32 + g * 8;
    const unsigned short* sp = src + ((size_t)lb * R + row) * KDv + col;
    unsigned short* dp = dst + (size_t)idx * 8;
#pragma unroll
    for (int j = 0; j < 8; ++j) dp[j] = sp[j];
}

// ---------------- matL W: fp32 -> packed bf16 fragments ----------------
// dst chunk flat = (((b*32+nt)*32+ms)*2+fn)*64 + lane; element j = Wg[b][nt*32+fn*16+r][ms*32+g*8+j]
__global__ __launch_bounds__(256) void k_wpack2(const float* __restrict__ Wg,
                                                unsigned short* __restrict__ dst) {
    int idx = blockIdx.x * 256 + threadIdx.x;  // 1M chunks
    int lane = idx & 63;
    int t = idx >> 6;
    int fn = t & 1; t >>= 1;
    int ms = t & 31; t >>= 5;
    int nt = t & 31;
    int b = t >> 5;
    int r = lane & 15, g = lane >> 4;
    const float* sp = &Wg[((size_t)b * NN + nt * 32 + fn * 16 + r) * NN + ms * 32 + g * 8];
    float v[8];
    *reinterpret_cast<float4*>(&v[0]) = *reinterpret_cast<const float4*>(sp);
    *reinterpret_cast<float4*>(&v[4]) = *reinterpret_cast<const float4*>(sp + 4);
    unsigned short* dp = dst + (size_t)idx * 8;
#pragma unroll
    for (int j = 0; j < 8; ++j) dp[j] = f2bf(v[j]);
}

// bks[lb][o][k] = sum_i Win[lb][o][i][k] * Bias[lb][i]   (exact fp32 bias folding)
__global__ __launch_bounds__(256) void k_prep_bks(const float* __restrict__ Win,
                                                  const float* __restrict__ Bias,
                                                  float* __restrict__ bks) {
    int idx = blockIdx.x * 256 + threadIdx.x;
    const int total = NL * 2 * CC * KS;
    if (idx >= total) return;
    int k = idx % KS;
    int t = idx / KS;
    int o = t % CC;
    int lb = t / CC;
    float s = 0.f;
    for (int i = 0; i < CH; ++i)
        s += Win[(((size_t)lb * CC + o) * CH + i) * KS + k] * Bias[lb * CH + i];
    bks[idx] = s;
}

// ---------------- open: Z = Kopen @ Zin * mask ----------------
__global__ __launch_bounds__(256) void k_open(const float* __restrict__ Zin,
                                              const float* __restrict__ mask,
                                              const float* __restrict__ Kop,
                                              float* __restrict__ Zcur) {
    int n = blockIdx.x * 256 + threadIdx.x;
    int c = blockIdx.y, b = blockIdx.z;
    float acc = 0.f;
    for (int i = 0; i < CIN; ++i)
        acc += Kop[c * CIN + i] * Zin[((size_t)b * CIN + i) * NN + n];
    Zcur[((size_t)b * CH + c) * NN + n] = acc * mask[b * NN + n];
}

// ---------------- Za ----------------
__global__ __launch_bounds__(256) void k_za(const float* __restrict__ Zcur,
                                            const float* __restrict__ mask,
                                            float* __restrict__ Za) {
    __shared__ float red[256];
    int c = blockIdx.x;  // 0..64
    int b = blockIdx.y;
    int tid = threadIdx.x;
    const float* m = mask + b * NN;
    float x[4], mv[4];
    if (c < CH) {
        const float* src = Zcur + ((size_t)b * CH + c) * NN;
#pragma unroll
        for (int j = 0; j < 4; ++j) { int n = tid * 4 + j; x[j] = src[n]; mv[j] = m[n]; }
    } else {
#pragma unroll
        for (int j = 0; j < 4; ++j) { int n = tid * 4 + j; mv[j] = m[n]; x[j] = 0.5f * ((float)n / 1023.f) * mv[j]; }
    }
    float sm = 0.f, sxm = 0.f;
#pragma unroll
    for (int j = 0; j < 4; ++j) { sm += mv[j]; sxm += x[j] * mv[j]; }
    float msum = blockSum(sm, red);
    float xm = blockSum(sxm, red);
    if (c < CH) {
        float mean = xm / msum;
        float ss = 0.f;
#pragma unroll
        for (int j = 0; j < 4; ++j) { x[j] -= mean * mv[j]; ss += x[j] * x[j]; }
        ss = blockSum(ss, red);
        float sc = rsqrtf(ss / msum + 1e-4f);
#pragma unroll
        for (int j = 0; j < 4; ++j) x[j] *= sc;
    }
    float ps = 0.f;
#pragma unroll
    for (int j = 0; j < 4; ++j) ps += x[j];
    float pm = blockSum(ps, red) / (float)NN;
    float* dst = Za + ((size_t)b * 65 + c) * NN;
#pragma unroll
    for (int j = 0; j < 4; ++j) dst[tid * 4 + j] = x[j] - pm;
}

// ---------------- n2 ----------------
__global__ __launch_bounds__(256) void k_n2g(const float* __restrict__ Za, float* __restrict__ n2g) {
    int n = blockIdx.x * 256 + threadIdx.x;
    int b = blockIdx.y;
    float s = 0.f;
    for (int c = 0; c < 65; ++c) { float v = Za[((size_t)b * 65 + c) * NN + n]; s += v * v; }
    n2g[b * NN + n] = s;
}

// ---------------- Gram + W ----------------
__global__ __launch_bounds__(256) void k_gramW(const float* __restrict__ Za,
                                               const float* __restrict__ n2g,
                                               const float* __restrict__ mask,
                                               float* __restrict__ Wg) {
    __shared__ float As[65][64];
    __shared__ float Bs2[65][64];
    int i0 = blockIdx.x * 64, j0 = blockIdx.y * 64, b = blockIdx.z;
    int tid = threadIdx.x;
    for (int e = tid; e < 65 * 64; e += 256) {
        int c = e >> 6, t = e & 63;
        const float* src = Za + ((size_t)b * 65 + c) * NN;
        As[c][t] = src[i0 + t];
        Bs2[c][t] = src[j0 + t];
    }
    __syncthreads();
    int tx = tid & 15, ty = tid >> 4;
    float acc[4][4] = {};
    for (int c = 0; c < 65; ++c) {
        float a[4];
#pragma unroll
        for (int q = 0; q < 4; ++q) a[q] = As[c][ty * 4 + q];
        float bv[4];
        *reinterpret_cast<float4*>(bv) = *reinterpret_cast<const float4*>(&Bs2[c][tx * 4]);
#pragma unroll
        for (int q = 0; q < 4; ++q)
#pragma unroll
            for (int r = 0; r < 4; ++r) acc[q][r] += a[q] * bv[r];
    }
    const float* m = mask + b * NN;
    for (int q = 0; q < 4; ++q) {
        int i = i0 + ty * 4 + q;
        float n2i = n2g[b * NN + i], mi = m[i];
        float res[4];
#pragma unroll
        for (int r = 0; r < 4; ++r) {
            int j = j0 + tx * 4 + r;
            float D = n2i + n2g[b * NN + j] - 2.f * acc[q][r];
            D *= (3.f / 65.f);
            D = fmaxf(D, 0.f);
            float dist = (D > 0.f) ? sqrtf(D) : 0.f;
            float mmv = mi * m[j];
            res[r] = expf(-dist * mmv) * mmv;
        }
        *reinterpret_cast<float4*>(&Wg[((size_t)b * NN + i) * NN + j0 + tx * 4]) =
            *reinterpret_cast<float4*>(res);
    }
}

// ---------------- Wsum: two-phase column sums ----------------
__global__ __launch_bounds__(256) void k_wsum_part(const float* __restrict__ Wg,
                                                   float* __restrict__ Wsp) {
    int j = blockIdx.x * 256 + threadIdx.x;
    int ch = blockIdx.y;   // 16 chunks of 64 rows
    int b = blockIdx.z;
    float s = 0.f;
    int i0 = ch * 64;
#pragma unroll 8
    for (int i = 0; i < 64; ++i) s += Wg[((size_t)b * NN + i0 + i) * NN + j];
    Wsp[((size_t)b * 16 + ch) * NN + j] = s;
}
__global__ __launch_bounds__(256) void k_wsum_fin(const float* __restrict__ Wsp,
                                                  float* __restrict__ Wsum) {
    int j = blockIdx.x * 256 + threadIdx.x;
    int b = blockIdx.y;
    float s = 0.f;
#pragma unroll
    for (int ch = 0; ch < 16; ++ch) s += Wsp[((size_t)b * 16 + ch) * NN + j];
    Wsum[b * NN + j] = s;
}

// ---------------- MFMA implicit-GEMM conv, hi/lo bf16, packed weights ----------------
// Weights packed: chunk = ((wtb + sg)*2 + fc)*512 + lane*8  (coalesced 16B/lane).
// X in LDS as uint = (lo16<<16)|hi16.  3 MFMAs per (fc,fn): hh, lh, hl.
// MODE 0 (conv1, KD=1024): y=(br<<1)|o_half; block 64o x 64n.
// MODE 1 (conv1T, KD=2048): y=(br<<1)|kh; partial out over kh.
template <int KD, int MODE>
__global__ __launch_bounds__(256) void k_conv_mfma(const float* __restrict__ InA,
                                                   const float* __restrict__ InB,
                                                   const unsigned short* __restrict__ Wh,
                                                   const unsigned short* __restrict__ Wlo,
                                                   const float* __restrict__ bksl,
                                                   const float* __restrict__ mask,
                                                   float* __restrict__ OutA0,
                                                   float* __restrict__ OutA1,
                                                   float* __restrict__ OutB0,
                                                   float* __restrict__ OutB1) {
    constexpr int XW = 80;   // 64 n + 16 halo, uints
    __shared__ __align__(16) unsigned int xs[64][XW];
    int n0 = blockIdx.x * 64;
    int y = blockIdx.y;
    int b = blockIdx.z;
    int tid = threadIdx.x;
    int wid = tid >> 6, lane = tid & 63;
    int wo = (wid >> 1) * 32, wn = (wid & 1) * 32;
    int r = lane & 15, g = lane >> 4;

    const float* Xb;
    float* Outp;
    const float* bo_base = nullptr;
    int domask = 0;
    int wtb, sg0;
    if (MODE == 0) {
        int br = y >> 1, ol = (y & 1) * 64;
        Xb = InA + (size_t)b * CH * NN;
        Outp = (br ? OutB0 : OutA0) + ((size_t)b * CC + ol) * NN;
        bo_base = bksl + (br * CC + ol) * KS;
        domask = (br == 0);
        wtb = (br * 4 + (y & 1) * 2 + (wid >> 1)) * 32;
        sg0 = 0;
    } else {
        int br = y >> 1, kh = y & 1;
        Xb = (br ? InB : InA) + (size_t)b * CC * NN + (size_t)kh * 64 * NN;
        float* o0 = br ? OutB0 : OutA0;
        float* o1 = br ? OutB1 : OutA1;
        Outp = (kh ? o1 : o0) + (size_t)b * CH * NN;
        wtb = (br * 2 + (wid >> 1)) * 64;
        sg0 = kh * 32;
    }

    // stage 64 rows x (64+16 halo) uints, hi/lo packed
    for (int e = tid * 4; e < 64 * XW; e += 1024) {
        int i = e / XW, t = e - i * XW;
        int gn = n0 + t - 4;
        float4 v = make_float4(0.f, 0.f, 0.f, 0.f);
        if (gn >= 0 && gn + 3 < NN) v = *reinterpret_cast<const float4*>(&Xb[(size_t)i * NN + gn]);
        uint4 u;
        unsigned short h;
        h = f2bf(v.x); u.x = (unsigned)h | ((unsigned)f2bf(v.x - bf2f(h)) << 16);
        h = f2bf(v.y); u.y = (unsigned)h | ((unsigned)f2bf(v.y - bf2f(h)) << 16);
        h = f2bf(v.z); u.z = (unsigned)h | ((unsigned)f2bf(v.z - bf2f(h)) << 16);
        h = f2bf(v.w); u.w = (unsigned)h | ((unsigned)f2bf(v.w - bf2f(h)) << 16);
        *reinterpret_cast<uint4*>(&xs[i][t]) = u;
    }
    __syncthreads();

    f32x4 acc[2][2] = {};
#pragma unroll 2
    for (int s = 0; s < 32; ++s) {
        int sg = sg0 + s;
        size_t widx = (size_t)(wtb + sg) * 1024 + lane * 8;
        bf16x8 ah[2], al[2];
        ah[0] = *reinterpret_cast<const bf16x8*>(&Wh[widx]);
        ah[1] = *reinterpret_cast<const bf16x8*>(&Wh[widx + 512]);
        al[0] = *reinterpret_cast<const bf16x8*>(&Wlo[widx]);
        al[1] = *reinterpret_cast<const bf16x8*>(&Wlo[widx + 512]);
        const unsigned int* xrow = xs[2 * s + (g >> 1)];
        int koff = (g & 1) << 3;
        bf16x8 bh[2], bl[2];
#pragma unroll
        for (int fn = 0; fn < 2; ++fn) {
            int off = wn + fn * 16 + r + koff;
            bf16x8 hh, ll;
#pragma unroll
            for (int j = 0; j < 8; ++j) {
                unsigned u = xrow[off + j];
                hh[j] = (short)(u & 0xFFFFu);
                ll[j] = (short)(u >> 16);
            }
            bh[fn] = hh;
            bl[fn] = ll;
        }
#pragma unroll
        for (int fc = 0; fc < 2; ++fc)
#pragma unroll
            for (int fn = 0; fn < 2; ++fn) {
                acc[fc][fn] = __builtin_amdgcn_mfma_f32_16x16x32_bf16(ah[fc], bh[fn], acc[fc][fn], 0, 0, 0);
                acc[fc][fn] = __builtin_amdgcn_mfma_f32_16x16x32_bf16(al[fc], bh[fn], acc[fc][fn], 0, 0, 0);
                acc[fc][fn] = __builtin_amdgcn_mfma_f32_16x16x32_bf16(ah[fc], bl[fn], acc[fc][fn], 0, 0, 0);
            }
    }

    const float* mrow = mask + b * NN;
#pragma unroll
    for (int fc = 0; fc < 2; ++fc) {
#pragma unroll
        for (int fn = 0; fn < 2; ++fn) {
            int n = n0 + wn + fn * 16 + r;
#pragma unroll
            for (int rr = 0; rr < 4; ++rr) {
                int oo = wo + fc * 16 + 4 * g + rr;
                float v = acc[fc][fn][rr];
                if (MODE == 0) {
                    const float* bo = bo_base + oo * KS;
                    float bias = 0.f;
#pragma unroll
                    for (int k = 0; k < KS; ++k) {
                        int nn2 = n + k - 4;
                        if (nn2 >= 0 && nn2 < NN) bias += bo[k];
                    }
                    v += bias;
                    if (domask) v *= mrow[n];
                }
                Outp[(size_t)oo * NN + n] = v;
            }
        }
    }
}

// ---------------- MFMA split-K X@W partials (packed W, bf16 LDS A) ----------------
__global__ __launch_bounds__(256) void k_matL_mfma(const float* __restrict__ X,
                                                   const float* __restrict__ XB,
                                                   const unsigned short* __restrict__ Wpk,
                                                   float* __restrict__ Part, int rows) {
    __shared__ __align__(16) unsigned short Xs[64][36];
    int cb = rows >> 6;
    int n0 = blockIdx.x * 64;
    int sk = blockIdx.y;
    int b = blockIdx.z / cb;
    int c0 = (blockIdx.z % cb) * 64;
    int tid = threadIdx.x;
    int wid = tid >> 6, lane = tid & 63;
    int wc = (wid >> 1) * 32;
    int r = lane & 15, g = lane >> 4;
    const float* Xb = X + (size_t)b * rows * NN;
    const float* Xb2 = XB ? XB + (size_t)b * rows * NN : nullptr;
    int nt32 = blockIdx.x * 2 + (wid & 1);
    const unsigned short* Wb = Wpk + ((size_t)b * 32 + nt32) * 32 * 1024;

    int srow = tid >> 2, scol = (tid & 3) * 8;   // staging map: 8 elems/thread
    f32x4 acc[2][2] = {};
    int m_beg = sk * (NN / SK);
    for (int m0 = m_beg; m0 < m_beg + NN / SK; m0 += 32) {
        {
            const float* sp = &Xb[(size_t)(c0 + srow) * NN + m0 + scol];
            float v[8];
            *reinterpret_cast<float4*>(&v[0]) = *reinterpret_cast<const float4*>(sp);
            *reinterpret_cast<float4*>(&v[4]) = *reinterpret_cast<const float4*>(sp + 4);
            if (Xb2) {
                const float* sp2 = &Xb2[(size_t)(c0 + srow) * NN + m0 + scol];
                float w[8];
                *reinterpret_cast<float4*>(&w[0]) = *reinterpret_cast<const float4*>(sp2);
                *reinterpret_cast<float4*>(&w[4]) = *reinterpret_cast<const float4*>(sp2 + 4);
#pragma unroll
                for (int j = 0; j < 8; ++j) v[j] += w[j];
            }
            unsigned short h[8];
#pragma unroll
            for (int j = 0; j < 8; ++j) h[j] = f2bf(v[j]);
            *reinterpret_cast<ushort4*>(&Xs[srow][scol]) = *reinterpret_cast<ushort4*>(&h[0]);
            *reinterpret_cast<ushort4*>(&Xs[srow][scol + 4]) = *reinterpret_cast<ushort4*>(&h[4]);
        }
        __syncthreads();
        bf16x8 afr[2];
#pragma unroll
        for (int fc = 0; fc < 2; ++fc) {
            const uint2* p = reinterpret_cast<const uint2*>(&Xs[wc + fc * 16 + r][8 * g]);
            uint2 q0 = p[0], q1 = p[1];
            union { unsigned int u[4]; bf16x8 v; } ua;
            ua.u[0] = q0.x; ua.u[1] = q0.y; ua.u[2] = q1.x; ua.u[3] = q1.y;
            afr[fc] = ua.v;
        }
        size_t wb = (size_t)(m0 >> 5) * 1024 + lane * 8;
        bf16x8 bfr[2];
        bfr[0] = *reinterpret_cast<const bf16x8*>(&Wb[wb]);
        bfr[1] = *reinterpret_cast<const bf16x8*>(&Wb[wb + 512]);
#pragma unroll
        for (int fc = 0; fc < 2; ++fc)
#pragma unroll
            for (int fn = 0; fn < 2; ++fn)
                acc[fc][fn] = __builtin_amdgcn_mfma_f32_16x16x32_bf16(afr[fc], bfr[fn], acc[fc][fn], 0, 0, 0);
        __syncthreads();
    }
    int wn = (wid & 1) * 32;
#pragma unroll
    for (int fc = 0; fc < 2; ++fc)
#pragma unroll
        for (int fn = 0; fn < 2; ++fn) {
            int ncol = n0 + wn + fn * 16 + r;
#pragma unroll
            for (int rr = 0; rr < 4; ++rr) {
                int crow = c0 + wc + fc * 16 + 4 * g + rr;
                Part[(((size_t)b * SK + sk) * rows + crow) * NN + ncol] = acc[fc][fn][rr];
            }
        }
}

// ---------------- reduce partials + epilogue ----------------
__global__ __launch_bounds__(256) void k_matL_fin(const float* __restrict__ X,
                                                  const float* __restrict__ XB,
                                                  const float* __restrict__ Part,
                                                  const float* __restrict__ Wsum,
                                                  const float* __restrict__ mask,
                                                  const float* __restrict__ T0A,
                                                  const float* __restrict__ T0B,
                                                  float* __restrict__ Out, int rows, int mode) {
    int idx = blockIdx.x * 256 + threadIdx.x;
    int b = blockIdx.y;
    if (idx >= rows * NN / 4) return;
    int c = idx / (NN / 4);
    int n = (idx % (NN / 4)) * 4;
    float4 s = make_float4(0.f, 0.f, 0.f, 0.f);
#pragma unroll
    for (int sk = 0; sk < SK; ++sk) {
        float4 p = *reinterpret_cast<const float4*>(
            &Part[(((size_t)b * SK + sk) * rows + c) * NN + n]);
        s.x += p.x; s.y += p.y; s.z += p.z; s.w += p.w;
    }
    float4 xv = *reinterpret_cast<const float4*>(&X[((size_t)b * rows + c) * NN + n]);
    if (XB) {
        float4 x2 = *reinterpret_cast<const float4*>(&XB[((size_t)b * rows + c) * NN + n]);
        xv.x += x2.x; xv.y += x2.y; xv.z += x2.z; xv.w += x2.w;
    }
    float4 wv = *reinterpret_cast<const float4*>(&Wsum[b * NN + n]);
    float4 mv = *reinterpret_cast<const float4*>(&mask[b * NN + n]);
    float y0 = xv.x * wv.x - s.x, y1 = xv.y * wv.y - s.y;
    float y2 = xv.z * wv.z - s.z, y3 = xv.w * wv.w - s.w;
    float4 res;
    if (mode == 0) {
        res = make_float4(y0 * mv.x, y1 * mv.y, y2 * mv.z, y3 * mv.w);
    } else {
        float4 t0 = *reinterpret_cast<const float4*>(&T0A[((size_t)b * rows + c) * NN + n]);
        float4 t0b = *reinterpret_cast<const float4*>(&T0B[((size_t)b * rows + c) * NN + n]);
        t0.x += t0b.x; t0.y += t0b.y; t0.z += t0b.z; t0.w += t0b.w;
        float4 o = *reinterpret_cast<const float4*>(&Out[((size_t)b * rows + c) * NN + n]);
        res = make_float4(o.x - HSTEP * mv.x * (t0.x + y0),
                          o.y - HSTEP * mv.y * (t0.y + y1),
                          o.z - HSTEP * mv.z * (t0.z + y2),
                          o.w - HSTEP * mv.w * (t0.w + y3));
    }
    *reinterpret_cast<float4*>(&Out[((size_t)b * rows + c) * NN + n]) = res;
}

// ---------------- masked row mean (two tensors fused) ----------------
__global__ __launch_bounds__(256) void k_rowmean2(const float* __restrict__ X0,
                                                  const float* __restrict__ X1,
                                                  const float* __restrict__ mask,
                                                  float* __restrict__ meanA) {
    __shared__ float red[256];
    int c = blockIdx.x, b = blockIdx.y, z = blockIdx.z, tid = threadIdx.x;
    const float* src = (z ? X1 : X0) + ((size_t)b * CC + c) * NN;
    const float* m = mask + b * NN;
    float s = 0.f, sm = 0.f;
    for (int n = tid; n < NN; n += 256) { float mv = m[n]; s += src[n] * mv; sm += mv; }
    float ts = blockSum(s, red);
    float tm = blockSum(sm, red);
    if (tid == 0) meanA[((size_t)z * BB + b) * CC + c] = ts / tm;
}

// ---------------- colnorm (32n x 8 c-groups per block) ----------------
__global__ __launch_bounds__(256) void k_colnorm2(float* __restrict__ X0,
                                                  float* __restrict__ X1,
                                                  const float* __restrict__ mask,
                                                  const float* __restrict__ meanA) {
    __shared__ float red[8][32];
    int tid = threadIdx.x;
    int nl = tid & 31, cg = tid >> 5;
    int n = blockIdx.x * 32 + nl;
    int b = blockIdx.y, z = blockIdx.z;
    float* X = (z ? X1 : X0) + (size_t)b * CC * NN;
    const float* me = meanA + ((size_t)z * BB + b) * CC;
    float mv = mask[b * NN + n];
    float ss = 0.f;
#pragma unroll
    for (int cc = 0; cc < 16; ++cc) {
        int c = cg * 16 + cc;
        float v = (X[(size_t)c * NN + n] - me[c]) * mv;
        ss += v * v;
    }
    red[cg][nl] = ss;
    __syncthreads();
    if (cg < 4) red[cg][nl] += red[cg + 4][nl];
    __syncthreads();
    if (cg < 2) red[cg][nl] += red[cg + 2][nl];
    __syncthreads();
    if (cg < 1) red[0][nl] += red[1][nl];
    __syncthreads();
    float inv = rsqrtf(red[0][nl] + 0.001f);
#pragma unroll
    for (int cc = 0; cc < 16; ++cc) {
        int c = cg * 16 + cc;
        float v = (X[(size_t)c * NN + n] - me[c]) * mv;
        X[(size_t)c * NN + n] = fmaxf(v * inv, 0.f);
    }
}

// ---------------- close (64n x 4 c-groups) ----------------
__global__ __launch_bounds__(256) void k_close(const float* __restrict__ Zcur,
                                               const float* __restrict__ Kcl,
                                               const float* __restrict__ mask,
                                               float* __restrict__ Zout) {
    __shared__ float red[4][64][COUT];
    int tid = threadIdx.x;
    int nl = tid & 63, cg = tid >> 6;
    int n = blockIdx.x * 64 + nl;
    int b = blockIdx.y;
    float acc[COUT] = {};
#pragma unroll
    for (int cc = 0; cc < 16; ++cc) {
        int c = cg * 16 + cc;
        float zv = Zcur[((size_t)b * CH + c) * NN + n];
#pragma unroll
        for (int o = 0; o < COUT; ++o) acc[o] += Kcl[o * CH + c] * zv;
    }
#pragma unroll
    for (int o = 0; o < COUT; ++o) red[cg][nl][o] = acc[o];
    __syncthreads();
    if (cg == 0) {
        float mv = mask[b * NN + n];
#pragma unroll
        for (int o = 0; o < COUT; ++o) {
            float s = red[0][nl][o] + red[1][nl][o] + red[2][nl][o] + red[3][nl][o];
            Zout[((size_t)b * COUT + o) * NN + n] = s * mv;
        }
    }
}

// ---------------- center3 ----------------
__global__ __launch_bounds__(256) void k_center3(const float* __restrict__ Zout, float* __restrict__ Zc3) {
    __shared__ float red[256];
    int c = blockIdx.x, b = blockIdx.y, tid = threadIdx.x;
    const float* src = Zout + ((size_t)b * COUT + c) * NN;
    float s = 0.f;
    for (int n = tid; n < NN; n += 256) s += src[n];
    float mean = blockSum(s, red) / (float)NN;
    float* dst = Zc3 + ((size_t)b * COUT + c) * NN;
    for (int n = tid; n < NN; n += 256) dst[n] = src[n] - mean;
}

__global__ __launch_bounds__(256) void k_n23(const float* __restrict__ Zc3, float* __restrict__ n23) {
    int n = blockIdx.x * 256 + threadIdx.x;
    int g = blockIdx.y, b = blockIdx.z;
    float s = 0.f;
#pragma unroll
    for (int c = 0; c < 3; ++c) { float v = Zc3[((size_t)b * COUT + g * 3 + c) * NN + n]; s += v * v; }
    n23[((size_t)b * 3 + g) * NN + n] = s;
}

// ---------------- final pairwise distances ----------------
__global__ __launch_bounds__(256) void k_dist(const float* __restrict__ Zc3,
                                              const float* __restrict__ n23,
                                              float* __restrict__ dout) {
    __shared__ float Ai[3][64], Aj[3][64], ni[64], nj[64];
    int bg = blockIdx.z;
    int b = bg / 3, g = bg - 3 * b;
    int i0 = blockIdx.x * 64, j0 = blockIdx.y * 64;
    int tid = threadIdx.x;
    if (tid < 64) ni[tid] = n23[((size_t)b * 3 + g) * NN + i0 + tid];
    else if (tid < 128) { int t = tid - 64; nj[t] = n23[((size_t)b * 3 + g) * NN + j0 + t]; }
    for (int e = tid; e < 192; e += 256) {
        int c = e / 64, t = e - c * 64;
        Ai[c][t] = Zc3[((size_t)b * COUT + g * 3 + c) * NN + i0 + t];
    }
    for (int e = tid; e < 192; e += 256) {
        int c = e / 64, t = e - c * 64;
        Aj[c][t] = Zc3[((size_t)b * COUT + g * 3 + c) * NN + j0 + t];
    }
    __syncthreads();
    int tx = tid & 15, ty = tid >> 4;
    for (int q = 0; q < 4; ++q) {
        int i = ty * 4 + q;
        float a0 = Ai[0][i], a1 = Ai[1][i], a2 = Ai[2][i], n2i = ni[i];
        float res[4];
#pragma unroll
        for (int r = 0; r < 4; ++r) {
            int j = tx * 4 + r;
            float D = n2i + nj[j] - 2.f * (a0 * Aj[0][j] + a1 * Aj[1][j] + a2 * Aj[2][j]);
            D = fmaxf(D, 0.f);
            res[r] = (D > 0.f) ? sqrtf(D) : 0.f;
        }
        *reinterpret_cast<float4*>(&dout[(((size_t)b * 3 + g) * NN + i0 + i) * NN + j0 + tx * 4]) =
            *reinterpret_cast<float4*>(res);
    }
}

// ---------------- driver ----------------
extern "C" void kernel_launch(void* const* d_in, const int* in_sizes, int n_in,
                              void* d_out, int out_size, void* d_ws, size_t ws_size,
                              hipStream_t stream) {
    (void)in_sizes; (void)n_in; (void)out_size; (void)ws_size;
    const float* Zin  = (const float*)d_in[0];
    const float* mask = (const float*)d_in[1];
    const float* Kop  = (const float*)d_in[2];
    const float* Kcl  = (const float*)d_in[3];
    const float* Win  = (const float*)d_in[4];
    const float* Bias = (const float*)d_in[5];
    float* out = (float*)d_out;
    float* ws = (float*)d_ws;

    size_t off = 0;
    float* Zcur = ws + off;  off += (size_t)BB * CH * NN;
    float* C0   = ws + off;  off += (size_t)BB * CC * NN;
    float* C1   = ws + off;  off += (size_t)BB * CC * NN;
    float* A1   = ws + off;  off += (size_t)BB * CC * NN;
    float* T0A  = ws + off;  off += (size_t)BB * CH * NN;
    float* T1pA = ws + off;  off += (size_t)BB * CH * NN;
    float* Za   = ws + off;  off += (size_t)BB * 65 * NN;
    float* n2g  = ws + off;  off += (size_t)BB * NN;
    float* Wg   = ws + off;  off += (size_t)BB * NN * NN;
    float* Wsum = ws + off;  off += (size_t)BB * NN;
    float* meanA= ws + off;  off += (size_t)2 * BB * CC;
    float* bks  = ws + off;  off += (size_t)NL * 2 * CC * KS;
    float* Zc3  = ws + off;  off += (size_t)BB * COUT * NN;
    float* n23  = ws + off;  off += (size_t)BB * 3 * NN;
    float* Wsp  = ws + off;  off += (size_t)BB * 16 * NN;

    // Scratch in the (as-yet-unwritten) dists region of d_out (25,165,824 floats):
    float* Part = out;                                                   // [0 .. 4,194,304)
    unsigned short* Wpk2  = (unsigned short*)(out + (size_t)4194304);    // matL packed W (8.4M bf16)
    unsigned short* Wpch  = (unsigned short*)(out + (size_t)8388608);    // row-major stages
    unsigned short* Wpcl  = (unsigned short*)(out + (size_t)9699328);
    unsigned short* Wpth  = (unsigned short*)(out + (size_t)11010048);
    unsigned short* Wptl  = (unsigned short*)(out + (size_t)12320768);
    float* T0B  = out + (size_t)13631488;
    float* T1pB = out + (size_t)14155776;
    unsigned short* PKc_h = (unsigned short*)(out + (size_t)14680064);   // packed conv weights
    unsigned short* PKc_l = (unsigned short*)(out + (size_t)15990784);
    unsigned short* PKt_h = (unsigned short*)(out + (size_t)17301504);
    unsigned short* PKt_l = (unsigned short*)(out + (size_t)18612224);

    const int wtot = NL * 2 * CC * CH * 16;  // 2,621,440 shorts per tensor
    k_prep_wbf<<<dim3((wtot + 255) / 256), 256, 0, stream>>>(Win, Wpch, Wpcl, Wpth, Wptl);
    k_packw<<<dim3(wtot / 8 / 256), 256, 0, stream>>>(Wpch, PKc_h, CC, 1024, NL * 2);
    k_packw<<<dim3(wtot / 8 / 256), 256, 0, stream>>>(Wpcl, PKc_l, CC, 1024, NL * 2);
    k_packw<<<dim3(wtot / 8 / 256), 256, 0, stream>>>(Wpth, PKt_h, CH, 2048, NL * 2);
    k_packw<<<dim3(wtot / 8 / 256), 256, 0, stream>>>(Wptl, PKt_l, CH, 2048, NL * 2);
    k_prep_bks<<<dim3((NL * 2 * CC * KS + 255) / 256), 256, 0, stream>>>(Win, Bias, bks);
    k_open<<<dim3(NN / 256, CH, BB), 256, 0, stream>>>(Zin, mask, Kop, Zcur);
    k_za<<<dim3(65, BB), 256, 0, stream>>>(Zcur, mask, Za);
    k_n2g<<<dim3(NN / 256, BB), 256, 0, stream>>>(Za, n2g);
    k_gramW<<<dim3(16, 16, BB), 256, 0, stream>>>(Za, n2g, mask, Wg);
    k_wsum_part<<<dim3(NN / 256, 16, BB), 256, 0, stream>>>(Wg, Wsp);
    k_wsum_fin<<<dim3(NN / 256, BB), 256, 0, stream>>>(Wsp, Wsum);
    k_wpack2<<<dim3((int)((size_t)BB * NN * NN / 8 / 256)), 256, 0, stream>>>(Wg, Wpk2);

    for (int l = 0; l < NL; ++l) {
        const unsigned short* PKc_h_l = PKc_h + (size_t)l * 2 * CC * 1024;
        const unsigned short* PKc_l_l = PKc_l + (size_t)l * 2 * CC * 1024;
        const unsigned short* PKt_h_l = PKt_h + (size_t)l * 2 * CH * 2048;
        const unsigned short* PKt_l_l = PKt_l + (size_t)l * 2 * CH * 2048;
        const float* bksl = bks + (size_t)l * 2 * CC * KS;

        k_conv_mfma<1024, 0><<<dim3(NN / 64, 4, BB), 256, 0, stream>>>(
            Zcur, nullptr, PKc_h_l, PKc_l_l, bksl, mask, C0, nullptr, C1, nullptr);
        k_matL_mfma<<<dim3(NN / 64, SK, BB * (CC / 64)), 256, 0, stream>>>(C1, nullptr, Wpk2, Part, CC);
        k_matL_fin<<<dim3(CC * NN / 4 / 256, BB), 256, 0, stream>>>(
            C1, nullptr, Part, Wsum, mask, nullptr, nullptr, A1, CC, 0);
        k_rowmean2<<<dim3(CC, BB, 2), 256, 0, stream>>>(C0, A1, mask, meanA);
        k_colnorm2<<<dim3(NN / 32, BB, 2), 256, 0, stream>>>(C0, A1, mask, meanA);
        k_conv_mfma<2048, 1><<<dim3(NN / 64, 4, BB), 256, 0, stream>>>(
            C0, A1, PKt_h_l, PKt_l_l, nullptr, mask, T0A, T0B, T1pA, T1pB);
        k_matL_mfma<<<dim3(NN / 64, SK, BB * (CH / 64)), 256, 0, stream>>>(T1pA, T1pB, Wpk2, Part, CH);
        k_matL_fin<<<dim3(CH * NN / 4 / 256, BB), 256, 0, stream>>>(
            T1pA, T1pB, Part, Wsum, mask, T0A, T0B, Zcur, CH, 1);
    }

    float* Zout = out + (size_t)BB * 3 * NN * NN;
    k_close<<<dim3(NN / 64, BB), 256, 0, stream>>>(Zcur, Kcl, mask, Zout);
    k_center3<<<dim3(COUT, BB), 256, 0, stream>>>(Zout, Zc3);
    k_n23<<<dim3(NN / 256, 3, BB), 256, 0, stream>>>(Zc3, n23);
    k_dist<<<dim3(16, 16, 3 * BB), 256, 0, stream>>>(Zc3, n23, out);
}